// Round 1
// baseline (132.363 us; speedup 1.0000x reference)
//
#include <hip/hip_runtime.h>
#include <math.h>

// Problem constants (fixed by the reference).
#define M_PTS 16384
#define N_PTS 16384
#define TPB 256
#define SPLITS 32                       // train-dim splits for parallelism
#define CHUNK_N (N_PTS / SPLITS)        // 512 train points per block
#define PTS_PER_THREAD 2
#define TEST_BLOCKS (M_PTS / (TPB * PTS_PER_THREAD))  // 32

__device__ __forceinline__ float fexp2(float x) {
#if __has_builtin(__builtin_amdgcn_exp2f)
    return __builtin_amdgcn_exp2f(x);   // v_exp_f32
#else
    return exp2f(x);
#endif
}

// Native fp32 global atomic add (device scope), no dependence on
// -munsafe-fp-atomics or header-provided unsafeAtomicAdd.
__device__ __forceinline__ void gatomic_fadd(float* p, float v) {
    asm volatile("global_atomic_add_f32 %0, %1, off" :: "v"(p), "v"(v) : "memory");
}

// Pass 1: stage per-train-point values so the hot loop is minimal.
// staged[n] = (-2c*t0, -2c*t1, c*|t|^2, sf2*a0);  a1s[n] = sf2*a1
// where c = -0.5/ell^2 * log2(e)  (so K = sf2 * exp2(c*sq)).
__global__ void stage_kernel(const float* __restrict__ Xtr,
                             const float* __restrict__ alpha,
                             const float* __restrict__ log_ell,
                             const float* __restrict__ log_sf,
                             float4* __restrict__ staged,
                             float* __restrict__ a1s) {
    int n = blockIdx.x * blockDim.x + threadIdx.x;
    if (n >= N_PTS) return;
    float ell = expf(log_ell[0]);
    float sf2 = expf(2.0f * log_sf[0]);
    float c = -0.5f / (ell * ell) * 1.4426950408889634f;  // * log2(e)
    float t0 = Xtr[2 * n], t1 = Xtr[2 * n + 1];
    float a0 = alpha[2 * n], a1 = alpha[2 * n + 1];
    staged[n] = make_float4(-2.0f * c * t0, -2.0f * c * t1,
                            c * (t0 * t0 + t1 * t1), sf2 * a0);
    a1s[n] = sf2 * a1;
}

// Pass 2: each thread owns 2 test points, scans a CHUNK_N slice of train
// points (uniform index -> scalar/broadcast loads), atomically adds partials.
__global__ __launch_bounds__(TPB) void gp_kernel(
        const float2* __restrict__ Xte,
        const float4* __restrict__ staged,
        const float* __restrict__ a1s,
        const float* __restrict__ log_ell,
        float* __restrict__ out) {
    int i0 = blockIdx.x * (TPB * PTS_PER_THREAD) + threadIdx.x;
    int i1 = i0 + TPB;
    float ell = expf(log_ell[0]);
    float c = -0.5f / (ell * ell) * 1.4426950408889634f;

    float2 xa = Xte[i0];
    float2 xb = Xte[i1];
    float bxa = c * (xa.x * xa.x + xa.y * xa.y);
    float bxb = c * (xb.x * xb.x + xb.y * xb.y);

    int j0 = blockIdx.y * CHUNK_N;
    float accA0 = 0.0f, accA1 = 0.0f, accB0 = 0.0f, accB1 = 0.0f;

#pragma unroll 4
    for (int j = j0; j < j0 + CHUNK_N; ++j) {
        float4 s = staged[j];     // wave-uniform address
        float a1 = a1s[j];
        // arg = c*sq; clamp sq>=0  <=>  arg<=0 (c<0)
        float ta = fminf(fmaf(s.x, xa.x, fmaf(s.y, xa.y, bxa + s.z)), 0.0f);
        float tb = fminf(fmaf(s.x, xb.x, fmaf(s.y, xb.y, bxb + s.z)), 0.0f);
        float ea = fexp2(ta);
        float eb = fexp2(tb);
        accA0 = fmaf(ea, s.w, accA0);
        accA1 = fmaf(ea, a1, accA1);
        accB0 = fmaf(eb, s.w, accB0);
        accB1 = fmaf(eb, a1, accB1);
    }

    gatomic_fadd(&out[2 * i0], accA0);
    gatomic_fadd(&out[2 * i0 + 1], accA1);
    gatomic_fadd(&out[2 * i1], accB0);
    gatomic_fadd(&out[2 * i1 + 1], accB1);
}

// Fallback if ws is too small to stage: recompute staged values in-loop.
__global__ __launch_bounds__(TPB) void gp_fallback(
        const float2* __restrict__ Xte,
        const float2* __restrict__ Xtr,
        const float2* __restrict__ alpha,
        const float* __restrict__ log_ell,
        const float* __restrict__ log_sf,
        float* __restrict__ out) {
    int i0 = blockIdx.x * (TPB * PTS_PER_THREAD) + threadIdx.x;
    int i1 = i0 + TPB;
    float ell = expf(log_ell[0]);
    float sf2 = expf(2.0f * log_sf[0]);
    float c = -0.5f / (ell * ell) * 1.4426950408889634f;

    float2 xa = Xte[i0];
    float2 xb = Xte[i1];
    float bxa = c * (xa.x * xa.x + xa.y * xa.y);
    float bxb = c * (xb.x * xb.x + xb.y * xb.y);

    int j0 = blockIdx.y * CHUNK_N;
    float accA0 = 0.0f, accA1 = 0.0f, accB0 = 0.0f, accB1 = 0.0f;

#pragma unroll 4
    for (int j = j0; j < j0 + CHUNK_N; ++j) {
        float2 t = Xtr[j];
        float2 a = alpha[j];
        float s0 = -2.0f * c * t.x;
        float s1 = -2.0f * c * t.y;
        float s2 = c * (t.x * t.x + t.y * t.y);
        float ta = fminf(fmaf(s0, xa.x, fmaf(s1, xa.y, bxa + s2)), 0.0f);
        float tb = fminf(fmaf(s0, xb.x, fmaf(s1, xb.y, bxb + s2)), 0.0f);
        float ea = fexp2(ta);
        float eb = fexp2(tb);
        accA0 = fmaf(ea, a.x, accA0);
        accA1 = fmaf(ea, a.y, accA1);
        accB0 = fmaf(eb, a.x, accB0);
        accB1 = fmaf(eb, a.y, accB1);
    }

    gatomic_fadd(&out[2 * i0], sf2 * accA0);
    gatomic_fadd(&out[2 * i0 + 1], sf2 * accA1);
    gatomic_fadd(&out[2 * i1], sf2 * accB0);
    gatomic_fadd(&out[2 * i1 + 1], sf2 * accB1);
}

extern "C" void kernel_launch(void* const* d_in, const int* in_sizes, int n_in,
                              void* d_out, int out_size, void* d_ws, size_t ws_size,
                              hipStream_t stream) {
    const float* Xte = (const float*)d_in[0];      // (M,2)
    const float* Xtr = (const float*)d_in[1];      // (N,2)
    const float* alpha = (const float*)d_in[2];    // (N,2)
    const float* log_ell = (const float*)d_in[3];  // scalar
    const float* log_sf = (const float*)d_in[4];   // scalar
    float* out = (float*)d_out;                    // (M,2)

    // d_out is poisoned before every call; we accumulate with atomics.
    hipMemsetAsync(out, 0, (size_t)out_size * sizeof(float), stream);

    dim3 grid(TEST_BLOCKS, SPLITS);
    size_t staged_bytes = (size_t)N_PTS * sizeof(float4) + (size_t)N_PTS * sizeof(float);
    if (ws_size >= staged_bytes) {
        float4* staged = (float4*)d_ws;
        float* a1s = (float*)((char*)d_ws + (size_t)N_PTS * sizeof(float4));
        stage_kernel<<<N_PTS / 256, 256, 0, stream>>>(Xtr, alpha, log_ell, log_sf,
                                                      staged, a1s);
        gp_kernel<<<grid, TPB, 0, stream>>>((const float2*)Xte, staged, a1s,
                                            log_ell, out);
    } else {
        gp_fallback<<<grid, TPB, 0, stream>>>((const float2*)Xte, (const float2*)Xtr,
                                              (const float2*)alpha, log_ell, log_sf,
                                              out);
    }
}

// Round 2
// 122.488 us; speedup vs baseline: 1.0806x; 1.0806x over previous
//
#include <hip/hip_runtime.h>
#include <math.h>

// Problem constants (fixed by the reference).
#define M_PTS 16384
#define N_PTS 16384
#define TPB 256
#define SPLITS 128                       // train-dim splits for parallelism
#define CHUNK_N (N_PTS / SPLITS)         // 128 train points per block
#define PTS 4                            // test points per thread
#define TEST_BLOCKS (M_PTS / (TPB * PTS))  // 16
// grid = (16, 128) = 2048 blocks x 4 waves = 8192 waves = 32 waves/CU (full).

__device__ __forceinline__ float fexp2(float x) {
#if __has_builtin(__builtin_amdgcn_exp2f)
    return __builtin_amdgcn_exp2f(x);   // v_exp_f32
#else
    return exp2f(x);
#endif
}

// Native fp32 global atomic add (device scope) for the ws-too-small fallback.
__device__ __forceinline__ void gatomic_fadd(float* p, float v) {
    asm volatile("global_atomic_add_f32 %0, %1, off" :: "v"(p), "v"(v) : "memory");
}

// Fused kernel: block (bx, by) handles test points [bx*1024, bx*1024+1024)
// against train chunk [by*128, by*128+128).
// Staging (per-train precompute) is done once into LDS by the first 128
// threads; the hot loop reads wave-uniform LDS (broadcast, no conflicts).
//   staged[j] = (-2c*t0, -2c*t1, c*|t|^2, sf2*a0), a1s[j] = sf2*a1,
//   c = -0.5/ell^2 * log2(e);  K = sf2 * exp2(min(c*sq, 0)).
template <bool ATOMIC>
__global__ __launch_bounds__(TPB, 8) void gp_fused(
        const float2* __restrict__ Xte,
        const float2* __restrict__ Xtr,
        const float2* __restrict__ alpha,
        const float* __restrict__ log_ell,
        const float* __restrict__ log_sf,
        float2* __restrict__ outp) {   // ws partials (ATOMIC=false) or out (true)
    __shared__ float4 sSt[CHUNK_N];
    __shared__ float  sA1[CHUNK_N];

    const int tid = threadIdx.x;
    const float ell = expf(log_ell[0]);
    const float c = -0.5f / (ell * ell) * 1.4426950408889634f;  // * log2(e)

    const int j0 = blockIdx.y * CHUNK_N;
    if (tid < CHUNK_N) {
        const float sf2 = expf(2.0f * log_sf[0]);
        float2 t = Xtr[j0 + tid];
        float2 a = alpha[j0 + tid];
        sSt[tid] = make_float4(-2.0f * c * t.x, -2.0f * c * t.y,
                               c * (t.x * t.x + t.y * t.y), sf2 * a.x);
        sA1[tid] = sf2 * a.y;
    }

    const int base = blockIdx.x * (TPB * PTS) + tid;
    float2 x0 = Xte[base];
    float2 x1 = Xte[base + TPB];
    float2 x2 = Xte[base + 2 * TPB];
    float2 x3 = Xte[base + 3 * TPB];
    const float b0 = c * (x0.x * x0.x + x0.y * x0.y);
    const float b1 = c * (x1.x * x1.x + x1.y * x1.y);
    const float b2 = c * (x2.x * x2.x + x2.y * x2.y);
    const float b3 = c * (x3.x * x3.x + x3.y * x3.y);

    __syncthreads();

    float a00 = 0.f, a01 = 0.f, a10 = 0.f, a11 = 0.f;
    float a20 = 0.f, a21 = 0.f, a30 = 0.f, a31 = 0.f;

#pragma unroll 2
    for (int j = 0; j < CHUNK_N; ++j) {
        float4 s = sSt[j];           // broadcast ds_read_b128
        float w1 = sA1[j];
        // arg = c*sq; clamp sq>=0  <=>  arg<=0 (since c<0)
        float t0 = fminf(fmaf(s.x, x0.x, fmaf(s.y, x0.y, b0 + s.z)), 0.0f);
        float t1 = fminf(fmaf(s.x, x1.x, fmaf(s.y, x1.y, b1 + s.z)), 0.0f);
        float t2 = fminf(fmaf(s.x, x2.x, fmaf(s.y, x2.y, b2 + s.z)), 0.0f);
        float t3 = fminf(fmaf(s.x, x3.x, fmaf(s.y, x3.y, b3 + s.z)), 0.0f);
        float e0 = fexp2(t0);
        float e1 = fexp2(t1);
        float e2 = fexp2(t2);
        float e3 = fexp2(t3);
        a00 = fmaf(e0, s.w, a00); a01 = fmaf(e0, w1, a01);
        a10 = fmaf(e1, s.w, a10); a11 = fmaf(e1, w1, a11);
        a20 = fmaf(e2, s.w, a20); a21 = fmaf(e2, w1, a21);
        a30 = fmaf(e3, s.w, a30); a31 = fmaf(e3, w1, a31);
    }

    if (ATOMIC) {
        float* o = (float*)outp;
        gatomic_fadd(&o[2 * base], a00);            gatomic_fadd(&o[2 * base + 1], a01);
        gatomic_fadd(&o[2 * (base + TPB)], a10);     gatomic_fadd(&o[2 * (base + TPB) + 1], a11);
        gatomic_fadd(&o[2 * (base + 2 * TPB)], a20); gatomic_fadd(&o[2 * (base + 2 * TPB) + 1], a21);
        gatomic_fadd(&o[2 * (base + 3 * TPB)], a30); gatomic_fadd(&o[2 * (base + 3 * TPB) + 1], a31);
    } else {
        float2* w = outp + (size_t)blockIdx.y * M_PTS;  // [split][point] as float2
        w[base]           = make_float2(a00, a01);
        w[base + TPB]     = make_float2(a10, a11);
        w[base + 2 * TPB] = make_float2(a20, a21);
        w[base + 3 * TPB] = make_float2(a30, a31);
    }
}

// Sum the SPLITS partials per test point. 16384 threads, coalesced float2.
__global__ __launch_bounds__(TPB) void reduce_kernel(
        const float2* __restrict__ ws, float2* __restrict__ out) {
    int i = blockIdx.x * blockDim.x + threadIdx.x;   // 0..M_PTS-1
    float sx = 0.f, sy = 0.f;
#pragma unroll 8
    for (int k = 0; k < SPLITS; ++k) {
        float2 v = ws[(size_t)k * M_PTS + i];
        sx += v.x;
        sy += v.y;
    }
    out[i] = make_float2(sx, sy);
}

extern "C" void kernel_launch(void* const* d_in, const int* in_sizes, int n_in,
                              void* d_out, int out_size, void* d_ws, size_t ws_size,
                              hipStream_t stream) {
    const float2* Xte = (const float2*)d_in[0];    // (M,2)
    const float2* Xtr = (const float2*)d_in[1];    // (N,2)
    const float2* alpha = (const float2*)d_in[2];  // (N,2)
    const float* log_ell = (const float*)d_in[3];  // scalar
    const float* log_sf = (const float*)d_in[4];   // scalar

    dim3 grid(TEST_BLOCKS, SPLITS);
    const size_t need = (size_t)SPLITS * M_PTS * sizeof(float2);  // 16.8 MB

    if (ws_size >= need) {
        float2* partials = (float2*)d_ws;
        gp_fused<false><<<grid, TPB, 0, stream>>>(Xte, Xtr, alpha, log_ell, log_sf,
                                                  partials);
        reduce_kernel<<<M_PTS / TPB, TPB, 0, stream>>>(partials, (float2*)d_out);
    } else {
        hipMemsetAsync(d_out, 0, (size_t)out_size * sizeof(float), stream);
        gp_fused<true><<<grid, TPB, 0, stream>>>(Xte, Xtr, alpha, log_ell, log_sf,
                                                 (float2*)d_out);
    }
}